// Round 6
// baseline (202.867 us; speedup 1.0000x reference)
//
#include <hip/hip_runtime.h>
#include <math.h>

#define NT 2
#define BSZ 4
#define NAT 512
#define NATOMS 2048
#define NNEI 200
#define EMB 100
#define FITH 240
#define DDIM 1600
#define TBK 1024

// ---- ws layout ----
// float region: [0..8) table ranges; [16..1552) concat biases (3x512); [1552..2064) w3c
#define BIAS_F  16
#define W3C_F   (BIAS_F + 3 * 512)
#define USH_BYTE 8320
// ushort region (offsets in ushorts from u0):
#define TBL_U   0                          // 4*1024*100 = 409600
#define W0T_U   409600                     // [512][1600] = 819200
#define W1T_U   (W0T_U + 819200)           // [512][512]  = 262144
#define W2T_U   (W1T_U + 262144)           // 262144
#define D_U     (W2T_U + 262144)           // [2048][1600] = 3276800
#define H0_U    (D_U + 3276800)            // [2048][512] = 1048576
#define H1_U    (H0_U + 1048576)           // 1048576
#define USH_END (H1_U + 1048576)
#define WS_NEED ((size_t)USH_BYTE + (size_t)USH_END * 2)   // ~14.3 MB

typedef short s8v __attribute__((ext_vector_type(8)));
typedef float f4v __attribute__((ext_vector_type(4)));

__device__ __forceinline__ float ftanh(float x) {
    float ax = fabsf(x);
    float e = __expf(2.0f * ax);
    float t = 1.0f - __fdividef(2.0f, e + 1.0f);
    return (x < 0.0f) ? -t : t;
}
__device__ __forceinline__ unsigned short f2bf(float f) {
    unsigned u = __float_as_uint(f);
    u += 0x7FFFu + ((u >> 16) & 1u);
    return (unsigned short)(u >> 16);
}
__device__ __forceinline__ float bf2f(unsigned short s) {
    return __uint_as_float(((unsigned)s) << 16);
}
__device__ __forceinline__ float calc_S(float R) {
    float Rsafe = (R > 1e-5f) ? R : 1.0f;
    float u = (R - 0.5f) * (1.0f / 5.5f);
    float uu = u * u;
    float mid = (u * uu * (-6.0f * uu + 15.0f * u - 10.0f) + 1.0f) / Rsafe;
    float S = 0.0f;
    if (R > 0.0f && R < 0.5f)      S = 1.0f / Rsafe;
    else if (R > 0.5f && R < 6.0f) S = mid;
    return S;
}

// ---------- K1: build bf16 concat weights (coalesced writes) + biases + w3c + Ei init ----------
#define N_W0 819200
#define N_W1 262144
#define N_W2 262144
#define N_B  1536
#define N_W3 512
#define N_EI 2048
__global__ void wtrans_kernel(const float* __restrict__ fW0, const float* __restrict__ fW1,
                              const float* __restrict__ fW2,
                              const float* __restrict__ fb0, const float* __restrict__ fb1,
                              const float* __restrict__ fb2,
                              const float* __restrict__ fW3, const float* __restrict__ fb3,
                              const float* __restrict__ eshift, const int* __restrict__ itype,
                              float* __restrict__ ws, float* __restrict__ out) {
    unsigned short* u0 = (unsigned short*)((char*)ws + USH_BYTE);
    int id = blockIdx.x * 256 + threadIdx.x;
    if (id < N_W0) {
        int n = id / 1600, k = id - n * 1600;
        float v = 0.0f;
        if (n < 240)                  v = fW0[(size_t)k * 240 + n];
        else if (n >= 256 && n < 496) v = fW0[(size_t)(1600 + k) * 240 + (n - 256)];
        u0[W0T_U + id] = f2bf(v);
        return;
    }
    id -= N_W0;
    if (id < N_W1) {
        int n = id / 512, k = id - n * 512;
        float v = 0.0f;
        if (n < 240 && k < 240)       v = fW1[(size_t)k * 240 + n];
        else if (n >= 256 && n < 496 && k >= 256 && k < 496)
                                      v = fW1[(size_t)(240 + (k - 256)) * 240 + (n - 256)];
        u0[W1T_U + id] = f2bf(v);
        return;
    }
    id -= N_W1;
    if (id < N_W2) {
        int n = id / 512, k = id - n * 512;
        float v = 0.0f;
        if (n < 240 && k < 240)       v = fW2[(size_t)k * 240 + n];
        else if (n >= 256 && n < 496 && k >= 256 && k < 496)
                                      v = fW2[(size_t)(240 + (k - 256)) * 240 + (n - 256)];
        u0[W2T_U + id] = f2bf(v);
        return;
    }
    id -= N_W2;
    if (id < N_B) {
        int l = id / 512, n = id - l * 512;
        const float* fb = (l == 0) ? fb0 : (l == 1) ? fb1 : fb2;
        float v = 0.0f;
        if (n < 240)                  v = fb[n];
        else if (n >= 256 && n < 496) v = fb[240 + (n - 256)];
        ws[BIAS_F + l * 512 + n] = v;
        return;
    }
    id -= N_B;
    if (id < N_W3) {
        int n = id;
        float v = 0.0f;
        if (n < 240)                  v = fW3[n];
        else if (n >= 256 && n < 496) v = fW3[240 + (n - 256)];
        ws[W3C_F + n] = v;
        return;
    }
    id -= N_W3;
    if (id < N_EI) {
        int t = itype[id & (NAT - 1)];
        out[4 + id] = fb3[t] + eshift[t];   // Ei init; gemm2 atomically adds partial dots
    }
}

// ---------- K2: embedding-net table build (covering range from davg/dstd) ----------
__global__ void __launch_bounds__(256) table_kernel(
    const float* __restrict__ davg, const float* __restrict__ dstd,
    const float* __restrict__ eW0, const float* __restrict__ eb0,
    const float* __restrict__ eW1, const float* __restrict__ eb1,
    const float* __restrict__ eW2, const float* __restrict__ eb2,
    float* __restrict__ ws)
{
    __shared__ float los[100], his[100];
    __shared__ float rng[2];
    __shared__ float h0s[8][25];
    __shared__ float h1s[8][50];
    const int bx = blockIdx.x;               // 512 blocks: nid (4) x 128
    const int nid = bx >> 7;
    const int kb  = (bx & 127) * 8;
    const int t = nid >> 1, j = nid & 1;
    const int tid = threadIdx.x;

    if (tid < 100) {
        int m = j * 100 + tid;
        float av = davg[(t * NNEI + m) * 4];
        float sd = dstd[(t * NNEI + m) * 4];
        float inv = __fdividef(1.0f, sd);
        float a = (0.0f - av) * inv;         // S in [0,2] for this data
        float b = (2.0f - av) * inv;
        los[tid] = fminf(a, b);
        his[tid] = fmaxf(a, b);
    }
    __syncthreads();
    if (tid == 0) {
        float lo = los[0], hi = his[0];
        for (int i = 1; i < 100; ++i) { lo = fminf(lo, los[i]); hi = fmaxf(hi, his[i]); }
        rng[0] = lo; rng[1] = hi - lo;
        if (kb == 0) {
            ws[nid * 2] = lo;
            ws[nid * 2 + 1] = (float)(TBK - 1) / (hi - lo);
        }
    }
    __syncthreads();
    const float smin = rng[0], span = rng[1];
    const float* W0 = eW0 + nid * 25;
    const float* B0 = eb0 + nid * 25;
    if (tid < 200) {
        int q = tid / 25, a = tid % 25;
        float s = smin + span * ((float)(kb + q) * (1.0f / (TBK - 1)));
        h0s[q][a] = ftanh(fmaf(s, W0[a], B0[a]));
    }
    __syncthreads();
    const float* W1 = eW1 + nid * 1250;
    const float* B1 = eb1 + nid * 50;
    for (int idx = tid; idx < 400; idx += 256) {
        int q = idx / 50, cc = idx % 50;
        float acc = B1[cc];
#pragma unroll
        for (int a = 0; a < 25; ++a) acc = fmaf(h0s[q][a], W1[a * 50 + cc], acc);
        h1s[q][cc] = ftanh(acc) + h0s[q][(cc < 25) ? cc : cc - 25];
    }
    __syncthreads();
    const float* W2 = eW2 + nid * 5000;
    const float* B2 = eb2 + nid * 100;
    unsigned short* tblu = (unsigned short*)((char*)ws + USH_BYTE) + TBL_U;
    for (int idx = tid; idx < 800; idx += 256) {
        int q = idx / 100, c = idx % 100;
        float acc = B2[c];
#pragma unroll
        for (int a = 0; a < 50; ++a) acc = fmaf(h1s[q][a], W2[a * 100 + c], acc);
        float g = ftanh(acc) + h1s[q][(c < 50) ? c : c - 50];
        tblu[(size_t)(nid * TBK + kb + q) * 100 + c] = f2bf(g);
    }
}

// ---------- K3: embed (table interp) -> writes D bf16 [2048][1600] ----------
__global__ void __launch_bounds__(128) embed_kernel(
    const int* __restrict__ itype, const float* __restrict__ imagedr,
    const float* __restrict__ davg, const float* __restrict__ dstd,
    float* __restrict__ ws)
{
    __shared__ __align__(16) float4 srn[NNEI];
    __shared__ float sx[NNEI];
    __shared__ float part[2][400];
    const int atom = blockIdx.x;
    const int n = atom & (NAT - 1);
    const int tid = threadIdx.x;
    const int t = itype[n];
    unsigned short* u0 = (unsigned short*)((char*)ws + USH_BYTE);

    const float sm0 = ws[(t * 2 + 0) * 2], sc0 = ws[(t * 2 + 0) * 2 + 1];
    const float sm1 = ws[(t * 2 + 1) * 2], sc1 = ws[(t * 2 + 1) * 2 + 1];

    for (int m = tid; m < NNEI; m += 128) {
        float4 dr = ((const float4*)imagedr)[(size_t)atom * NNEI + m];
        float R = dr.x;
        float S = calc_S(R);
        float Rsafe = (R > 1e-5f) ? R : 1.0f;
        float sr = (fabsf(R) > 1e-5f) ? (S / Rsafe) : 0.0f;
        float4 av = ((const float4*)davg)[t * NNEI + m];
        float4 sd = ((const float4*)dstd)[t * NNEI + m];
        float4 rv;
        rv.x = (S         - av.x) / sd.x;
        rv.y = (sr * dr.y - av.y) / sd.y;
        rv.z = (sr * dr.z - av.z) / sd.z;
        rv.w = (sr * dr.w - av.w) / sd.w;
        srn[m] = rv;
        float smin = (m >= 100) ? sm1 : sm0;
        float scal = (m >= 100) ? sc1 : sc0;
        sx[m] = fminf(fmaxf((rv.x - smin) * scal, 0.0f), (float)(TBK - 2) + 0.9999f);
    }
    __syncthreads();

    const int w = tid >> 6, lane = tid & 63;
    const unsigned short* T = u0 + TBL_U + (size_t)(t * 2 + w) * TBK * EMB;
    const bool hi = (lane < 36);
    float xA0 = 0, xA1 = 0, xA2 = 0, xA3 = 0;
    float xB0 = 0, xB1 = 0, xB2 = 0, xB3 = 0;
#pragma unroll 2
    for (int mi = 0; mi < 100; ++mi) {
        int m = w * 100 + mi;
        float4 rv = srn[m];
        float x = sx[m];
        int i = (int)x;
        float f = x - (float)i;
        const unsigned short* Tr = T + (size_t)i * EMB;
        float g0 = bf2f(Tr[lane]);
        float g1 = bf2f(Tr[EMB + lane]);
        float g = fmaf(f, g1 - g0, g0);
        xA0 = fmaf(rv.x, g, xA0); xA1 = fmaf(rv.y, g, xA1);
        xA2 = fmaf(rv.z, g, xA2); xA3 = fmaf(rv.w, g, xA3);
        if (hi) {
            float h0v = bf2f(Tr[64 + lane]);
            float h1v = bf2f(Tr[EMB + 64 + lane]);
            float g2 = fmaf(f, h1v - h0v, h0v);
            xB0 = fmaf(rv.x, g2, xB0); xB1 = fmaf(rv.y, g2, xB1);
            xB2 = fmaf(rv.z, g2, xB2); xB3 = fmaf(rv.w, g2, xB3);
        }
    }
    part[w][0 * 100 + lane] = xA0; part[w][1 * 100 + lane] = xA1;
    part[w][2 * 100 + lane] = xA2; part[w][3 * 100 + lane] = xA3;
    if (hi) {
        part[w][0 * 100 + 64 + lane] = xB0; part[w][1 * 100 + 64 + lane] = xB1;
        part[w][2 * 100 + 64 + lane] = xB2; part[w][3 * 100 + 64 + lane] = xB3;
    }
    __syncthreads();
    const float inv = 1.0f / 200.0f;
    for (int idx = tid; idx < 400; idx += 128)
        part[0][idx] = (part[0][idx] + part[1][idx]) * inv;   // xyz[4][100]
    __syncthreads();
    unsigned short* Drow = u0 + D_U + (size_t)atom * DDIM;
    const float* xt = part[0];
    for (int idx = tid; idx < DDIM; idx += 128) {
        int c = idx >> 4, d = idx & 15;
        float s = xt[c] * xt[d] + xt[100 + c] * xt[100 + d]
                + xt[200 + c] * xt[200 + d] + xt[300 + c] * xt[300 + d];
        Drow[idx] = f2bf(s);
    }
}

// ---------- K4: barrier-free single-wave GEMM, 16x32 C-tile per wave ----------
// mode 0: Out = tanh(A x BT^T + bias)
// mode 1: Out = Res + tanh(A x BT^T + bias)
// mode 2: fused final dot: atomicAdd per-row (Res + tanh(.))·w3c, type-masked
__global__ void __launch_bounds__(64) gemm16_kernel(
    const unsigned short* __restrict__ A, int lda,
    const unsigned short* __restrict__ BT, int ldb,
    const float* __restrict__ bias,
    const unsigned short* __restrict__ Res,
    unsigned short* __restrict__ Out, int ldo,
    const float* __restrict__ w3c, const int* __restrict__ itype,
    float* __restrict__ out,
    int ksteps, int diag, int mode)
{
    const int lane = threadIdx.x;
    const int bx = blockIdx.x;      // n-tile of 32 (0..15)
    const int by = blockIdx.y;      // m-tile of 16 (0..127)
    const int m0 = by * 16, n0 = bx * 32;
    const int k0 = (diag && bx >= 8) ? 256 : 0;
    const int mr = lane & 15;
    const int q  = lane >> 4;
    const unsigned short* Ap  = A  + (size_t)(m0 + mr) * lda + k0 + q * 8;
    const unsigned short* B0p = BT + (size_t)(n0 + mr) * ldb + k0 + q * 8;
    const unsigned short* B1p = B0p + (size_t)16 * ldb;

    f4v acc0 = {0.0f, 0.0f, 0.0f, 0.0f};
    f4v acc1 = {0.0f, 0.0f, 0.0f, 0.0f};
#pragma unroll 2
    for (int kt = 0; kt < ksteps; ++kt) {
        s8v av = *(const s8v*)(Ap  + kt * 32);
        s8v b0 = *(const s8v*)(B0p + kt * 32);
        s8v b1 = *(const s8v*)(B1p + kt * 32);
        acc0 = __builtin_amdgcn_mfma_f32_16x16x32_bf16(av, b0, acc0, 0, 0, 0);
        acc1 = __builtin_amdgcn_mfma_f32_16x16x32_bf16(av, b1, acc1, 0, 0, 0);
    }

    const int g0 = n0 + mr, g1 = n0 + 16 + mr;
    const float bv0 = bias[g0], bv1 = bias[g1];
    if (mode < 2) {
#pragma unroll
        for (int r = 0; r < 4; ++r) {
            int row = m0 + q * 4 + r;
            size_t i0 = (size_t)row * ldo + g0;
            size_t i1 = (size_t)row * ldo + g1;
            float v0 = ftanh(acc0[r] + bv0);
            float v1 = ftanh(acc1[r] + bv1);
            if (mode == 1) { v0 += bf2f(Res[i0]); v1 += bf2f(Res[i1]); }
            Out[i0] = f2bf(v0); Out[i1] = f2bf(v1);
        }
    } else {
        const int seg = (bx >= 8);
        const float w30 = w3c[g0], w31 = w3c[g1];
#pragma unroll
        for (int r = 0; r < 4; ++r) {
            int row = m0 + q * 4 + r;
            size_t i0 = (size_t)row * ldo + g0;
            size_t i1 = (size_t)row * ldo + g1;
            float v0 = bf2f(Res[i0]) + ftanh(acc0[r] + bv0);
            float v1 = bf2f(Res[i1]) + ftanh(acc1[r] + bv1);
            float p = v0 * w30 + v1 * w31;
            p += __shfl_xor(p, 1, 16);
            p += __shfl_xor(p, 2, 16);
            p += __shfl_xor(p, 4, 16);
            p += __shfl_xor(p, 8, 16);
            if (mr == 0 && itype[row & (NAT - 1)] == seg)
                atomicAdd(&out[4 + row], p);
        }
    }
}

// ---------- K5: Etot over Ei ----------
__global__ void etot_kernel(float* __restrict__ out) {
    const int b = blockIdx.x;
    float s = 0.0f;
    for (int n = threadIdx.x; n < NAT; n += 256) s += out[4 + b * NAT + n];
#pragma unroll
    for (int off = 32; off > 0; off >>= 1) s += __shfl_down(s, off, 64);
    __shared__ float rr[4];
    if ((threadIdx.x & 63) == 0) rr[threadIdx.x >> 6] = s;
    __syncthreads();
    if (threadIdx.x == 0) out[b] = rr[0] + rr[1] + rr[2] + rr[3];
}

// ================= fallback (small ws): monolithic per-atom =================
__global__ void dp_atom_kernel(
    const int* __restrict__ itype, const float* __restrict__ imagedr,
    const float* __restrict__ davg, const float* __restrict__ dstd,
    const float* __restrict__ eW0, const float* __restrict__ eb0,
    const float* __restrict__ eW1, const float* __restrict__ eb1,
    const float* __restrict__ eW2, const float* __restrict__ eb2,
    const float* __restrict__ fW0, const float* __restrict__ fb0,
    const float* __restrict__ fW1, const float* __restrict__ fb1,
    const float* __restrict__ fW2, const float* __restrict__ fb2,
    const float* __restrict__ fW3, const float* __restrict__ fb3,
    const float* __restrict__ eshift, float* __restrict__ out)
{
    __shared__ __align__(16) float4 rn4[NNEI];
    __shared__ __align__(16) float  xyz[4 * EMB];
    __shared__ __align__(16) float  h0s[100 * 25];
    __shared__ __align__(16) float  smem[100 * 52];
    const int atom = blockIdx.x;
    const int n = atom & (NAT - 1);
    const int tid = threadIdx.x;
    const int t = itype[n];
    for (int m = tid; m < NNEI; m += 256) {
        float4 dr = ((const float4*)imagedr)[(size_t)atom * NNEI + m];
        float R = dr.x;
        float S = calc_S(R);
        float Rsafe = (R > 1e-5f) ? R : 1.0f;
        float sr = (fabsf(R) > 1e-5f) ? (S / Rsafe) : 0.0f;
        float4 av = ((const float4*)davg)[t * NNEI + m];
        float4 sd = ((const float4*)dstd)[t * NNEI + m];
        float4 rv;
        rv.x = (S - av.x) / sd.x; rv.y = (sr * dr.y - av.y) / sd.y;
        rv.z = (sr * dr.z - av.z) / sd.z; rv.w = (sr * dr.w - av.w) / sd.w;
        rn4[m] = rv;
    }
    const int c = tid & 127; const int mh = tid >> 7;
    float xp0 = 0, xp1 = 0, xp2 = 0, xp3 = 0;
    for (int j = 0; j < NT; ++j) {
        const int wb = t * NT + j;
        const float* W0 = eW0 + wb * 25; const float* B0 = eb0 + wb * 25;
        const float* W1 = eW1 + wb * 1250; const float* B1 = eb1 + wb * 50;
        const float* W2 = eW2 + wb * 5000; const float* B2 = eb2 + wb * 100;
        __syncthreads();
        for (int idx = tid; idx < 2500; idx += 256) {
            int m = idx / 25, a = idx - m * 25;
            h0s[idx] = ftanh(fmaf(rn4[j * 100 + m].x, W0[a], B0[a]));
        }
        __syncthreads();
        for (int idx = tid; idx < 5000; idx += 256) {
            int m = idx / 50, cc = idx - m * 50;
            const float* h0m = h0s + m * 25;
            float acc = B1[cc];
#pragma unroll
            for (int a = 0; a < 25; ++a) acc = fmaf(h0m[a], W1[a * 50 + cc], acc);
            smem[m * 52 + cc] = ftanh(acc) + h0m[(cc < 25) ? cc : cc - 25];
        }
        for (int idx = tid; idx < 200; idx += 256)
            smem[(idx >> 1) * 52 + 50 + (idx & 1)] = 0.0f;
        __syncthreads();
        if (c < EMB) {
            float w2c[52];
#pragma unroll
            for (int a = 0; a < 50; ++a) w2c[a] = W2[a * EMB + c];
            w2c[50] = 0; w2c[51] = 0;
            const float bc = B2[c];
            const int sk = (c < 50) ? c : c - 50;
            for (int i = 0; i < 50; ++i) {
                int m = mh * 50 + i;
                const float* h1m = smem + m * 52;
                float acc = bc;
#pragma unroll
                for (int q = 0; q < 13; ++q) {
                    float4 hv = ((const float4*)h1m)[q];
                    acc = fmaf(hv.x, w2c[4 * q], acc); acc = fmaf(hv.y, w2c[4 * q + 1], acc);
                    acc = fmaf(hv.z, w2c[4 * q + 2], acc); acc = fmaf(hv.w, w2c[4 * q + 3], acc);
                }
                float g = ftanh(acc) + h1m[sk];
                float4 rm = rn4[j * 100 + m];
                xp0 = fmaf(rm.x, g, xp0); xp1 = fmaf(rm.y, g, xp1);
                xp2 = fmaf(rm.z, g, xp2); xp3 = fmaf(rm.w, g, xp3);
            }
        }
    }
    __syncthreads();
    const float inv = 1.0f / 200.0f;
    if (mh == 0 && c < EMB) {
        xyz[c] = xp0 * inv; xyz[EMB + c] = xp1 * inv;
        xyz[2 * EMB + c] = xp2 * inv; xyz[3 * EMB + c] = xp3 * inv;
    }
    __syncthreads();
    if (mh == 1 && c < EMB) {
        xyz[c] += xp0 * inv; xyz[EMB + c] += xp1 * inv;
        xyz[2 * EMB + c] += xp2 * inv; xyz[3 * EMB + c] += xp3 * inv;
    }
    __syncthreads();
    float* Dld = smem;
    for (int idx = tid; idx < DDIM; idx += 256) {
        int cc = idx >> 4, d = idx & 15;
        Dld[idx] = xyz[cc] * xyz[d] + xyz[EMB + cc] * xyz[EMB + d]
                 + xyz[2 * EMB + cc] * xyz[2 * EMB + d] + xyz[3 * EMB + cc] * xyz[3 * EMB + d];
    }
    __syncthreads();
    float* hA = smem + DDIM; float* hB = hA + FITH; float* h2 = hB + FITH; float* red = h2 + FITH;
    if (tid < FITH) {
        const float* W = fW0 + (size_t)t * DDIM * FITH;
        float acc = fb0[t * FITH + tid];
        for (int f = 0; f < DDIM; f += 4) {
            float4 dv = *(const float4*)(Dld + f);
            acc = fmaf(dv.x, W[f * FITH + tid], acc); acc = fmaf(dv.y, W[(f + 1) * FITH + tid], acc);
            acc = fmaf(dv.z, W[(f + 2) * FITH + tid], acc); acc = fmaf(dv.w, W[(f + 3) * FITH + tid], acc);
        }
        hA[tid] = ftanh(acc);
    }
    __syncthreads();
    if (tid < FITH) {
        const float* W = fW1 + t * FITH * FITH;
        float acc = fb1[t * FITH + tid];
        for (int f = 0; f < FITH; f += 4) {
            float4 hv = *(const float4*)(hA + f);
            acc = fmaf(hv.x, W[f * FITH + tid], acc); acc = fmaf(hv.y, W[(f + 1) * FITH + tid], acc);
            acc = fmaf(hv.z, W[(f + 2) * FITH + tid], acc); acc = fmaf(hv.w, W[(f + 3) * FITH + tid], acc);
        }
        hB[tid] = hA[tid] + ftanh(acc);
    }
    __syncthreads();
    if (tid < FITH) {
        const float* W = fW2 + t * FITH * FITH;
        float acc = fb2[t * FITH + tid];
        for (int f = 0; f < FITH; f += 4) {
            float4 hv = *(const float4*)(hB + f);
            acc = fmaf(hv.x, W[f * FITH + tid], acc); acc = fmaf(hv.y, W[(f + 1) * FITH + tid], acc);
            acc = fmaf(hv.z, W[(f + 2) * FITH + tid], acc); acc = fmaf(hv.w, W[(f + 3) * FITH + tid], acc);
        }
        h2[tid] = hB[tid] + ftanh(acc);
    }
    __syncthreads();
    float p = (tid < FITH) ? h2[tid] * fW3[t * FITH + tid] : 0.0f;
#pragma unroll
    for (int off = 32; off > 0; off >>= 1) p += __shfl_down(p, off, 64);
    if ((tid & 63) == 0) red[tid >> 6] = p;
    __syncthreads();
    if (tid == 0) out[4 + atom] = red[0] + red[1] + red[2] + red[3] + fb3[t] + eshift[t];
}

extern "C" void kernel_launch(void* const* d_in, const int* in_sizes, int n_in,
                              void* d_out, int out_size, void* d_ws, size_t ws_size,
                              hipStream_t stream) {
    const int*   itype   = (const int*)  d_in[1];
    const float* imagedr = (const float*)d_in[3];
    const float* davg    = (const float*)d_in[5];
    const float* dstd    = (const float*)d_in[6];
    const float* eW0     = (const float*)d_in[7];
    const float* eb0     = (const float*)d_in[8];
    const float* eW1     = (const float*)d_in[9];
    const float* eb1     = (const float*)d_in[10];
    const float* eW2     = (const float*)d_in[11];
    const float* eb2     = (const float*)d_in[12];
    const float* fW0     = (const float*)d_in[13];
    const float* fb0     = (const float*)d_in[14];
    const float* fW1     = (const float*)d_in[15];
    const float* fb1     = (const float*)d_in[16];
    const float* fW2     = (const float*)d_in[17];
    const float* fb2     = (const float*)d_in[18];
    const float* fW3     = (const float*)d_in[19];
    const float* fb3     = (const float*)d_in[20];
    const float* eshift  = (const float*)d_in[21];
    float* out = (float*)d_out;
    float* ws  = (float*)d_ws;

    if (ws_size >= WS_NEED) {
        unsigned short* u0 = (unsigned short*)((char*)ws + USH_BYTE);
        const int n_ids = N_W0 + N_W1 + N_W2 + N_B + N_W3 + N_EI;
        wtrans_kernel<<<(n_ids + 255) / 256, 256, 0, stream>>>(
            fW0, fW1, fW2, fb0, fb1, fb2, fW3, fb3, eshift, itype, ws, out);
        table_kernel<<<512, 256, 0, stream>>>(davg, dstd, eW0, eb0, eW1, eb1, eW2, eb2, ws);
        embed_kernel<<<NATOMS, 128, 0, stream>>>(itype, imagedr, davg, dstd, ws);
        // layer 0: H0 = tanh(D x W0 + b0)
        gemm16_kernel<<<dim3(16, 128), 64, 0, stream>>>(
            u0 + D_U, DDIM, u0 + W0T_U, DDIM, ws + BIAS_F,
            nullptr, u0 + H0_U, 512, nullptr, nullptr, nullptr, 50, 0, 0);
        // layer 1: H1 = H0 + tanh(H0 x W1 + b1)
        gemm16_kernel<<<dim3(16, 128), 64, 0, stream>>>(
            u0 + H0_U, 512, u0 + W1T_U, 512, ws + BIAS_F + 512,
            u0 + H0_U, u0 + H1_U, 512, nullptr, nullptr, nullptr, 8, 1, 0 + 1);
        // layer 2 fused with final dot: Ei += ((H1 + tanh(H1 x W2 + b2)) . w3c) [type-masked]
        gemm16_kernel<<<dim3(16, 128), 64, 0, stream>>>(
            u0 + H1_U, 512, u0 + W2T_U, 512, ws + BIAS_F + 1024,
            u0 + H1_U, nullptr, 512, ws + W3C_F, itype, out, 8, 1, 2);
        etot_kernel<<<BSZ, 256, 0, stream>>>(out);
    } else {
        dp_atom_kernel<<<NATOMS, 256, 0, stream>>>(itype, imagedr, davg, dstd,
            eW0, eb0, eW1, eb1, eW2, eb2,
            fW0, fb0, fW1, fb1, fW2, fb2, fW3, fb3, eshift, out);
        etot_kernel<<<BSZ, 256, 0, stream>>>(out);
    }
}

// Round 7
// 192.330 us; speedup vs baseline: 1.0548x; 1.0548x over previous
//
#include <hip/hip_runtime.h>
#include <math.h>

#define NT 2
#define BSZ 4
#define NAT 512
#define NATOMS 2048
#define NNEI 200
#define EMB 100
#define FITH 240
#define DDIM 1600
#define TBK 1024

// ---- ws layout ----
#define BIAS_F  16
#define W3C_F   (BIAS_F + 3 * 512)
#define USH_BYTE 8320
#define TBL_U   0                          // 4*1024*100 = 409600
#define W0T_U   409600                     // [512][1600] = 819200
#define W1T_U   (W0T_U + 819200)           // [512][512]  = 262144
#define W2T_U   (W1T_U + 262144)           // 262144
#define D_U     (W2T_U + 262144)           // [2048][1600] = 3276800
#define H0_U    (D_U + 3276800)            // [2048][512] = 1048576
#define H1_U    (H0_U + 1048576)           // 1048576
#define USH_END (H1_U + 1048576)
#define WS_NEED ((size_t)USH_BYTE + (size_t)USH_END * 2)   // ~14.3 MB

typedef short s8v __attribute__((ext_vector_type(8)));
typedef float f4v __attribute__((ext_vector_type(4)));

__device__ __forceinline__ float ftanh(float x) {
    float ax = fabsf(x);
    float e = __expf(2.0f * ax);
    float t = 1.0f - __fdividef(2.0f, e + 1.0f);
    return (x < 0.0f) ? -t : t;
}
__device__ __forceinline__ unsigned short f2bf(float f) {
    unsigned u = __float_as_uint(f);
    u += 0x7FFFu + ((u >> 16) & 1u);
    return (unsigned short)(u >> 16);
}
__device__ __forceinline__ float bf2f(unsigned short s) {
    return __uint_as_float(((unsigned)s) << 16);
}
__device__ __forceinline__ float calc_S(float R) {
    float Rsafe = (R > 1e-5f) ? R : 1.0f;
    float u = (R - 0.5f) * (1.0f / 5.5f);
    float uu = u * u;
    float mid = (u * uu * (-6.0f * uu + 15.0f * u - 10.0f) + 1.0f) / Rsafe;
    float S = 0.0f;
    if (R > 0.0f && R < 0.5f)      S = 1.0f / Rsafe;
    else if (R > 0.5f && R < 6.0f) S = mid;
    return S;
}

// ---------- K1: bf16 concat weights + biases + w3c + Ei init ----------
#define N_W0 819200
#define N_W1 262144
#define N_W2 262144
#define N_B  1536
#define N_W3 512
#define N_EI 2048
__global__ void wtrans_kernel(const float* __restrict__ fW0, const float* __restrict__ fW1,
                              const float* __restrict__ fW2,
                              const float* __restrict__ fb0, const float* __restrict__ fb1,
                              const float* __restrict__ fb2,
                              const float* __restrict__ fW3, const float* __restrict__ fb3,
                              const float* __restrict__ eshift, const int* __restrict__ itype,
                              float* __restrict__ ws, float* __restrict__ out) {
    unsigned short* u0 = (unsigned short*)((char*)ws + USH_BYTE);
    int id = blockIdx.x * 256 + threadIdx.x;
    if (id < N_W0) {
        int n = id / 1600, k = id - n * 1600;
        float v = 0.0f;
        if (n < 240)                  v = fW0[(size_t)k * 240 + n];
        else if (n >= 256 && n < 496) v = fW0[(size_t)(1600 + k) * 240 + (n - 256)];
        u0[W0T_U + id] = f2bf(v);
        return;
    }
    id -= N_W0;
    if (id < N_W1) {
        int n = id / 512, k = id - n * 512;
        float v = 0.0f;
        if (n < 240 && k < 240)       v = fW1[(size_t)k * 240 + n];
        else if (n >= 256 && n < 496 && k >= 256 && k < 496)
                                      v = fW1[(size_t)(240 + (k - 256)) * 240 + (n - 256)];
        u0[W1T_U + id] = f2bf(v);
        return;
    }
    id -= N_W1;
    if (id < N_W2) {
        int n = id / 512, k = id - n * 512;
        float v = 0.0f;
        if (n < 240 && k < 240)       v = fW2[(size_t)k * 240 + n];
        else if (n >= 256 && n < 496 && k >= 256 && k < 496)
                                      v = fW2[(size_t)(240 + (k - 256)) * 240 + (n - 256)];
        u0[W2T_U + id] = f2bf(v);
        return;
    }
    id -= N_W2;
    if (id < N_B) {
        int l = id / 512, n = id - l * 512;
        const float* fb = (l == 0) ? fb0 : (l == 1) ? fb1 : fb2;
        float v = 0.0f;
        if (n < 240)                  v = fb[n];
        else if (n >= 256 && n < 496) v = fb[240 + (n - 256)];
        ws[BIAS_F + l * 512 + n] = v;
        return;
    }
    id -= N_B;
    if (id < N_W3) {
        int n = id;
        float v = 0.0f;
        if (n < 240)                  v = fW3[n];
        else if (n >= 256 && n < 496) v = fW3[240 + (n - 256)];
        ws[W3C_F + n] = v;
        return;
    }
    id -= N_W3;
    if (id < N_EI) {
        int t = itype[id & (NAT - 1)];
        out[4 + id] = fb3[t] + eshift[t];
    }
}

// ---------- K2: embedding-net table build ----------
__global__ void __launch_bounds__(256) table_kernel(
    const float* __restrict__ davg, const float* __restrict__ dstd,
    const float* __restrict__ eW0, const float* __restrict__ eb0,
    const float* __restrict__ eW1, const float* __restrict__ eb1,
    const float* __restrict__ eW2, const float* __restrict__ eb2,
    float* __restrict__ ws)
{
    __shared__ float los[100], his[100];
    __shared__ float rng[2];
    __shared__ float h0s[8][25];
    __shared__ float h1s[8][50];
    const int bx = blockIdx.x;               // 512 blocks: nid (4) x 128
    const int nid = bx >> 7;
    const int kb  = (bx & 127) * 8;
    const int t = nid >> 1, j = nid & 1;
    const int tid = threadIdx.x;

    if (tid < 100) {
        int m = j * 100 + tid;
        float av = davg[(t * NNEI + m) * 4];
        float sd = dstd[(t * NNEI + m) * 4];
        float inv = __fdividef(1.0f, sd);
        float a = (0.0f - av) * inv;         // S in [0,2] for this data
        float b = (2.0f - av) * inv;
        los[tid] = fminf(a, b);
        his[tid] = fmaxf(a, b);
    }
    __syncthreads();
    if (tid == 0) {
        float lo = los[0], hi = his[0];
        for (int i = 1; i < 100; ++i) { lo = fminf(lo, los[i]); hi = fmaxf(hi, his[i]); }
        rng[0] = lo; rng[1] = hi - lo;
        if (kb == 0) {
            ws[nid * 2] = lo;
            ws[nid * 2 + 1] = (float)(TBK - 1) / (hi - lo);
        }
    }
    __syncthreads();
    const float smin = rng[0], span = rng[1];
    const float* W0 = eW0 + nid * 25;
    const float* B0 = eb0 + nid * 25;
    if (tid < 200) {
        int q = tid / 25, a = tid % 25;
        float s = smin + span * ((float)(kb + q) * (1.0f / (TBK - 1)));
        h0s[q][a] = ftanh(fmaf(s, W0[a], B0[a]));
    }
    __syncthreads();
    const float* W1 = eW1 + nid * 1250;
    const float* B1 = eb1 + nid * 50;
    for (int idx = tid; idx < 400; idx += 256) {
        int q = idx / 50, cc = idx % 50;
        float acc = B1[cc];
#pragma unroll
        for (int a = 0; a < 25; ++a) acc = fmaf(h0s[q][a], W1[a * 50 + cc], acc);
        h1s[q][cc] = ftanh(acc) + h0s[q][(cc < 25) ? cc : cc - 25];
    }
    __syncthreads();
    const float* W2 = eW2 + nid * 5000;
    const float* B2 = eb2 + nid * 100;
    unsigned short* tblu = (unsigned short*)((char*)ws + USH_BYTE) + TBL_U;
    for (int idx = tid; idx < 800; idx += 256) {
        int q = idx / 100, c = idx % 100;
        float acc = B2[c];
#pragma unroll
        for (int a = 0; a < 50; ++a) acc = fmaf(h1s[q][a], W2[a * 100 + c], acc);
        float g = ftanh(acc) + h1s[q][(c < 50) ? c : c - 50];
        tblu[(size_t)(nid * TBK + kb + q) * 100 + c] = f2bf(g);
    }
}

// ---------- K3: embed (table interp) -> D bf16 [2048][1600] ----------
__global__ void __launch_bounds__(128) embed_kernel(
    const int* __restrict__ itype, const float* __restrict__ imagedr,
    const float* __restrict__ davg, const float* __restrict__ dstd,
    float* __restrict__ ws)
{
    __shared__ __align__(16) float4 srn[NNEI];
    __shared__ float sx[NNEI];
    __shared__ float part[2][400];
    const int atom = blockIdx.x;
    const int n = atom & (NAT - 1);
    const int tid = threadIdx.x;
    const int t = itype[n];
    unsigned short* u0 = (unsigned short*)((char*)ws + USH_BYTE);

    const float sm0 = ws[(t * 2 + 0) * 2], sc0 = ws[(t * 2 + 0) * 2 + 1];
    const float sm1 = ws[(t * 2 + 1) * 2], sc1 = ws[(t * 2 + 1) * 2 + 1];

    for (int m = tid; m < NNEI; m += 128) {
        float4 dr = ((const float4*)imagedr)[(size_t)atom * NNEI + m];
        float R = dr.x;
        float S = calc_S(R);
        float Rsafe = (R > 1e-5f) ? R : 1.0f;
        float sr = (fabsf(R) > 1e-5f) ? (S / Rsafe) : 0.0f;
        float4 av = ((const float4*)davg)[t * NNEI + m];
        float4 sd = ((const float4*)dstd)[t * NNEI + m];
        float4 rv;
        rv.x = (S         - av.x) / sd.x;
        rv.y = (sr * dr.y - av.y) / sd.y;
        rv.z = (sr * dr.z - av.z) / sd.z;
        rv.w = (sr * dr.w - av.w) / sd.w;
        srn[m] = rv;
        float smin = (m >= 100) ? sm1 : sm0;
        float scal = (m >= 100) ? sc1 : sc0;
        sx[m] = fminf(fmaxf((rv.x - smin) * scal, 0.0f), (float)(TBK - 2) + 0.9999f);
    }
    __syncthreads();

    const int w = tid >> 6, lane = tid & 63;
    const unsigned short* T = u0 + TBL_U + (size_t)(t * 2 + w) * TBK * EMB;
    const bool hi = (lane < 36);
    float xA0 = 0, xA1 = 0, xA2 = 0, xA3 = 0;
    float xB0 = 0, xB1 = 0, xB2 = 0, xB3 = 0;
#pragma unroll 4
    for (int mi = 0; mi < 100; ++mi) {
        int m = w * 100 + mi;
        float4 rv = srn[m];
        float x = sx[m];
        int i = (int)x;
        float f = x - (float)i;
        const unsigned short* Tr = T + (size_t)i * EMB;
        float g0 = bf2f(Tr[lane]);
        float g1 = bf2f(Tr[EMB + lane]);
        float g = fmaf(f, g1 - g0, g0);
        xA0 = fmaf(rv.x, g, xA0); xA1 = fmaf(rv.y, g, xA1);
        xA2 = fmaf(rv.z, g, xA2); xA3 = fmaf(rv.w, g, xA3);
        if (hi) {
            float h0v = bf2f(Tr[64 + lane]);
            float h1v = bf2f(Tr[EMB + 64 + lane]);
            float g2 = fmaf(f, h1v - h0v, h0v);
            xB0 = fmaf(rv.x, g2, xB0); xB1 = fmaf(rv.y, g2, xB1);
            xB2 = fmaf(rv.z, g2, xB2); xB3 = fmaf(rv.w, g2, xB3);
        }
    }
    part[w][0 * 100 + lane] = xA0; part[w][1 * 100 + lane] = xA1;
    part[w][2 * 100 + lane] = xA2; part[w][3 * 100 + lane] = xA3;
    if (hi) {
        part[w][0 * 100 + 64 + lane] = xB0; part[w][1 * 100 + 64 + lane] = xB1;
        part[w][2 * 100 + 64 + lane] = xB2; part[w][3 * 100 + 64 + lane] = xB3;
    }
    __syncthreads();
    const float inv = 1.0f / 200.0f;
    for (int idx = tid; idx < 400; idx += 128)
        part[0][idx] = (part[0][idx] + part[1][idx]) * inv;   // xyz[4][100]
    __syncthreads();
    unsigned short* Drow = u0 + D_U + (size_t)atom * DDIM;
    const float* xt = part[0];
    for (int idx = tid; idx < DDIM; idx += 128) {
        int c = idx >> 4, d = idx & 15;
        float s = xt[c] * xt[d] + xt[100 + c] * xt[100 + d]
                + xt[200 + c] * xt[200 + d] + xt[300 + c] * xt[300 + d];
        Drow[idx] = f2bf(s);
    }
}

// ---------- K4a: layer-0 GEMM — 16x64 tile, 2-wave k-split, 4 acc chains ----------
__global__ void __launch_bounds__(128) gemm0_kernel(
    const unsigned short* __restrict__ A,     // D [2048][1600]
    const unsigned short* __restrict__ BT,    // W0T [512][1600]
    const float* __restrict__ bias,
    unsigned short* __restrict__ Out)         // H0 [2048][512]
{
    __shared__ float lred[64][17];
    const int tid = threadIdx.x;
    const int w = tid >> 6, lane = tid & 63;
    const int mr = lane & 15, q = lane >> 4;
    const int n0 = blockIdx.x * 64;           // 0..7
    const int m0 = blockIdx.y * 16;           // 0..127
    const unsigned short* Ap = A  + (size_t)(m0 + mr) * DDIM + w * 800 + q * 8;
    const unsigned short* Bp = BT + (size_t)(n0 + mr) * DDIM + w * 800 + q * 8;

    f4v a0 = {0,0,0,0}, a1 = {0,0,0,0}, a2 = {0,0,0,0}, a3 = {0,0,0,0};
#pragma unroll 5
    for (int kt = 0; kt < 25; ++kt) {
        s8v av = *(const s8v*)(Ap + kt * 32);
        s8v b0 = *(const s8v*)(Bp + kt * 32);
        s8v b1 = *(const s8v*)(Bp + 16 * DDIM + kt * 32);
        s8v b2 = *(const s8v*)(Bp + 32 * DDIM + kt * 32);
        s8v b3 = *(const s8v*)(Bp + 48 * DDIM + kt * 32);
        a0 = __builtin_amdgcn_mfma_f32_16x16x32_bf16(av, b0, a0, 0, 0, 0);
        a1 = __builtin_amdgcn_mfma_f32_16x16x32_bf16(av, b1, a1, 0, 0, 0);
        a2 = __builtin_amdgcn_mfma_f32_16x16x32_bf16(av, b2, a2, 0, 0, 0);
        a3 = __builtin_amdgcn_mfma_f32_16x16x32_bf16(av, b3, a3, 0, 0, 0);
    }
    if (w == 1) {
#pragma unroll
        for (int r = 0; r < 4; ++r) {
            lred[lane][r]      = a0[r];
            lred[lane][4 + r]  = a1[r];
            lred[lane][8 + r]  = a2[r];
            lred[lane][12 + r] = a3[r];
        }
    }
    __syncthreads();
    if (w == 0) {
#pragma unroll
        for (int j = 0; j < 4; ++j) {
            const int col = n0 + j * 16 + mr;
            const float bv = bias[col];
            f4v* ap = (j == 0) ? &a0 : (j == 1) ? &a1 : (j == 2) ? &a2 : &a3;
#pragma unroll
            for (int r = 0; r < 4; ++r) {
                float s = (*ap)[r] + lred[lane][j * 4 + r] + bv;
                int row = m0 + q * 4 + r;
                Out[(size_t)row * 512 + col] = f2bf(ftanh(s));
            }
        }
    }
}

// ---------- K4b: residual GEMM layers 1/2 — single wave, 16x64 tile ----------
// mode 1: Out = Res + tanh(A x BT^T + bias)
// mode 2: Ei += ((Res + tanh(.)) . w3c) per row, type-masked
__global__ void __launch_bounds__(64) gemmr_kernel(
    const unsigned short* __restrict__ A, const unsigned short* __restrict__ BT,
    const float* __restrict__ bias, const unsigned short* __restrict__ Res,
    unsigned short* __restrict__ Out,
    const float* __restrict__ w3c, const int* __restrict__ itype,
    float* __restrict__ out, int mode)
{
    const int lane = threadIdx.x;
    const int mr = lane & 15, q = lane >> 4;
    const int bx = blockIdx.x;                // 0..7
    const int n0 = bx * 64;
    const int m0 = blockIdx.y * 16;
    const int k0 = (bx >= 4) ? 256 : 0;
    const unsigned short* Ap = A  + (size_t)(m0 + mr) * 512 + k0 + q * 8;
    const unsigned short* Bp = BT + (size_t)(n0 + mr) * 512 + k0 + q * 8;

    f4v a0 = {0,0,0,0}, a1 = {0,0,0,0}, a2 = {0,0,0,0}, a3 = {0,0,0,0};
#pragma unroll
    for (int kt = 0; kt < 8; ++kt) {
        s8v av = *(const s8v*)(Ap + kt * 32);
        s8v b0 = *(const s8v*)(Bp + kt * 32);
        s8v b1 = *(const s8v*)(Bp + 16 * 512 + kt * 32);
        s8v b2 = *(const s8v*)(Bp + 32 * 512 + kt * 32);
        s8v b3 = *(const s8v*)(Bp + 48 * 512 + kt * 32);
        a0 = __builtin_amdgcn_mfma_f32_16x16x32_bf16(av, b0, a0, 0, 0, 0);
        a1 = __builtin_amdgcn_mfma_f32_16x16x32_bf16(av, b1, a1, 0, 0, 0);
        a2 = __builtin_amdgcn_mfma_f32_16x16x32_bf16(av, b2, a2, 0, 0, 0);
        a3 = __builtin_amdgcn_mfma_f32_16x16x32_bf16(av, b3, a3, 0, 0, 0);
    }
    const float bv0 = bias[n0 + mr],      bv1 = bias[n0 + 16 + mr];
    const float bv2 = bias[n0 + 32 + mr], bv3 = bias[n0 + 48 + mr];
    if (mode == 1) {
#pragma unroll
        for (int r = 0; r < 4; ++r) {
            int row = m0 + q * 4 + r;
            size_t base = (size_t)row * 512 + n0 + mr;
            Out[base]      = f2bf(bf2f(Res[base])      + ftanh(a0[r] + bv0));
            Out[base + 16] = f2bf(bf2f(Res[base + 16]) + ftanh(a1[r] + bv1));
            Out[base + 32] = f2bf(bf2f(Res[base + 32]) + ftanh(a2[r] + bv2));
            Out[base + 48] = f2bf(bf2f(Res[base + 48]) + ftanh(a3[r] + bv3));
        }
    } else {
        const int seg = (bx >= 4);
        const float w30 = w3c[n0 + mr],      w31 = w3c[n0 + 16 + mr];
        const float w32 = w3c[n0 + 32 + mr], w33 = w3c[n0 + 48 + mr];
#pragma unroll
        for (int r = 0; r < 4; ++r) {
            int row = m0 + q * 4 + r;
            size_t base = (size_t)row * 512 + n0 + mr;
            float p = (bf2f(Res[base])      + ftanh(a0[r] + bv0)) * w30
                    + (bf2f(Res[base + 16]) + ftanh(a1[r] + bv1)) * w31
                    + (bf2f(Res[base + 32]) + ftanh(a2[r] + bv2)) * w32
                    + (bf2f(Res[base + 48]) + ftanh(a3[r] + bv3)) * w33;
            p += __shfl_xor(p, 1, 16);
            p += __shfl_xor(p, 2, 16);
            p += __shfl_xor(p, 4, 16);
            p += __shfl_xor(p, 8, 16);
            if (mr == 0 && itype[row & (NAT - 1)] == seg)
                atomicAdd(&out[4 + row], p);
        }
    }
}

// ---------- K5: Etot over Ei ----------
__global__ void etot_kernel(float* __restrict__ out) {
    const int b = blockIdx.x;
    float s = 0.0f;
    for (int n = threadIdx.x; n < NAT; n += 256) s += out[4 + b * NAT + n];
#pragma unroll
    for (int off = 32; off > 0; off >>= 1) s += __shfl_down(s, off, 64);
    __shared__ float rr[4];
    if ((threadIdx.x & 63) == 0) rr[threadIdx.x >> 6] = s;
    __syncthreads();
    if (threadIdx.x == 0) out[b] = rr[0] + rr[1] + rr[2] + rr[3];
}

// ================= fallback (small ws): monolithic per-atom =================
__global__ void dp_atom_kernel(
    const int* __restrict__ itype, const float* __restrict__ imagedr,
    const float* __restrict__ davg, const float* __restrict__ dstd,
    const float* __restrict__ eW0, const float* __restrict__ eb0,
    const float* __restrict__ eW1, const float* __restrict__ eb1,
    const float* __restrict__ eW2, const float* __restrict__ eb2,
    const float* __restrict__ fW0, const float* __restrict__ fb0,
    const float* __restrict__ fW1, const float* __restrict__ fb1,
    const float* __restrict__ fW2, const float* __restrict__ fb2,
    const float* __restrict__ fW3, const float* __restrict__ fb3,
    const float* __restrict__ eshift, float* __restrict__ out)
{
    __shared__ __align__(16) float4 rn4[NNEI];
    __shared__ __align__(16) float  xyz[4 * EMB];
    __shared__ __align__(16) float  h0s[100 * 25];
    __shared__ __align__(16) float  smem[100 * 52];
    const int atom = blockIdx.x;
    const int n = atom & (NAT - 1);
    const int tid = threadIdx.x;
    const int t = itype[n];
    for (int m = tid; m < NNEI; m += 256) {
        float4 dr = ((const float4*)imagedr)[(size_t)atom * NNEI + m];
        float R = dr.x;
        float S = calc_S(R);
        float Rsafe = (R > 1e-5f) ? R : 1.0f;
        float sr = (fabsf(R) > 1e-5f) ? (S / Rsafe) : 0.0f;
        float4 av = ((const float4*)davg)[t * NNEI + m];
        float4 sd = ((const float4*)dstd)[t * NNEI + m];
        float4 rv;
        rv.x = (S - av.x) / sd.x; rv.y = (sr * dr.y - av.y) / sd.y;
        rv.z = (sr * dr.z - av.z) / sd.z; rv.w = (sr * dr.w - av.w) / sd.w;
        rn4[m] = rv;
    }
    const int c = tid & 127; const int mh = tid >> 7;
    float xp0 = 0, xp1 = 0, xp2 = 0, xp3 = 0;
    for (int j = 0; j < NT; ++j) {
        const int wb = t * NT + j;
        const float* W0 = eW0 + wb * 25; const float* B0 = eb0 + wb * 25;
        const float* W1 = eW1 + wb * 1250; const float* B1 = eb1 + wb * 50;
        const float* W2 = eW2 + wb * 5000; const float* B2 = eb2 + wb * 100;
        __syncthreads();
        for (int idx = tid; idx < 2500; idx += 256) {
            int m = idx / 25, a = idx - m * 25;
            h0s[idx] = ftanh(fmaf(rn4[j * 100 + m].x, W0[a], B0[a]));
        }
        __syncthreads();
        for (int idx = tid; idx < 5000; idx += 256) {
            int m = idx / 50, cc = idx - m * 50;
            const float* h0m = h0s + m * 25;
            float acc = B1[cc];
#pragma unroll
            for (int a = 0; a < 25; ++a) acc = fmaf(h0m[a], W1[a * 50 + cc], acc);
            smem[m * 52 + cc] = ftanh(acc) + h0m[(cc < 25) ? cc : cc - 25];
        }
        for (int idx = tid; idx < 200; idx += 256)
            smem[(idx >> 1) * 52 + 50 + (idx & 1)] = 0.0f;
        __syncthreads();
        if (c < EMB) {
            float w2c[52];
#pragma unroll
            for (int a = 0; a < 50; ++a) w2c[a] = W2[a * EMB + c];
            w2c[50] = 0; w2c[51] = 0;
            const float bc = B2[c];
            const int sk = (c < 50) ? c : c - 50;
            for (int i = 0; i < 50; ++i) {
                int m = mh * 50 + i;
                const float* h1m = smem + m * 52;
                float acc = bc;
#pragma unroll
                for (int q = 0; q < 13; ++q) {
                    float4 hv = ((const float4*)h1m)[q];
                    acc = fmaf(hv.x, w2c[4 * q], acc); acc = fmaf(hv.y, w2c[4 * q + 1], acc);
                    acc = fmaf(hv.z, w2c[4 * q + 2], acc); acc = fmaf(hv.w, w2c[4 * q + 3], acc);
                }
                float g = ftanh(acc) + h1m[sk];
                float4 rm = rn4[j * 100 + m];
                xp0 = fmaf(rm.x, g, xp0); xp1 = fmaf(rm.y, g, xp1);
                xp2 = fmaf(rm.z, g, xp2); xp3 = fmaf(rm.w, g, xp3);
            }
        }
    }
    __syncthreads();
    const float inv = 1.0f / 200.0f;
    if (mh == 0 && c < EMB) {
        xyz[c] = xp0 * inv; xyz[EMB + c] = xp1 * inv;
        xyz[2 * EMB + c] = xp2 * inv; xyz[3 * EMB + c] = xp3 * inv;
    }
    __syncthreads();
    if (mh == 1 && c < EMB) {
        xyz[c] += xp0 * inv; xyz[EMB + c] += xp1 * inv;
        xyz[2 * EMB + c] += xp2 * inv; xyz[3 * EMB + c] += xp3 * inv;
    }
    __syncthreads();
    float* Dld = smem;
    for (int idx = tid; idx < DDIM; idx += 256) {
        int cc = idx >> 4, d = idx & 15;
        Dld[idx] = xyz[cc] * xyz[d] + xyz[EMB + cc] * xyz[EMB + d]
                 + xyz[2 * EMB + cc] * xyz[2 * EMB + d] + xyz[3 * EMB + cc] * xyz[3 * EMB + d];
    }
    __syncthreads();
    float* hA = smem + DDIM; float* hB = hA + FITH; float* h2 = hB + FITH; float* red = h2 + FITH;
    if (tid < FITH) {
        const float* W = fW0 + (size_t)t * DDIM * FITH;
        float acc = fb0[t * FITH + tid];
        for (int f = 0; f < DDIM; f += 4) {
            float4 dv = *(const float4*)(Dld + f);
            acc = fmaf(dv.x, W[f * FITH + tid], acc); acc = fmaf(dv.y, W[(f + 1) * FITH + tid], acc);
            acc = fmaf(dv.z, W[(f + 2) * FITH + tid], acc); acc = fmaf(dv.w, W[(f + 3) * FITH + tid], acc);
        }
        hA[tid] = ftanh(acc);
    }
    __syncthreads();
    if (tid < FITH) {
        const float* W = fW1 + t * FITH * FITH;
        float acc = fb1[t * FITH + tid];
        for (int f = 0; f < FITH; f += 4) {
            float4 hv = *(const float4*)(hA + f);
            acc = fmaf(hv.x, W[f * FITH + tid], acc); acc = fmaf(hv.y, W[(f + 1) * FITH + tid], acc);
            acc = fmaf(hv.z, W[(f + 2) * FITH + tid], acc); acc = fmaf(hv.w, W[(f + 3) * FITH + tid], acc);
        }
        hB[tid] = hA[tid] + ftanh(acc);
    }
    __syncthreads();
    if (tid < FITH) {
        const float* W = fW2 + t * FITH * FITH;
        float acc = fb2[t * FITH + tid];
        for (int f = 0; f < FITH; f += 4) {
            float4 hv = *(const float4*)(hB + f);
            acc = fmaf(hv.x, W[f * FITH + tid], acc); acc = fmaf(hv.y, W[(f + 1) * FITH + tid], acc);
            acc = fmaf(hv.z, W[(f + 2) * FITH + tid], acc); acc = fmaf(hv.w, W[(f + 3) * FITH + tid], acc);
        }
        h2[tid] = hB[tid] + ftanh(acc);
    }
    __syncthreads();
    float p = (tid < FITH) ? h2[tid] * fW3[t * FITH + tid] : 0.0f;
#pragma unroll
    for (int off = 32; off > 0; off >>= 1) p += __shfl_down(p, off, 64);
    if ((tid & 63) == 0) red[tid >> 6] = p;
    __syncthreads();
    if (tid == 0) out[4 + atom] = red[0] + red[1] + red[2] + red[3] + fb3[t] + eshift[t];
}

extern "C" void kernel_launch(void* const* d_in, const int* in_sizes, int n_in,
                              void* d_out, int out_size, void* d_ws, size_t ws_size,
                              hipStream_t stream) {
    const int*   itype   = (const int*)  d_in[1];
    const float* imagedr = (const float*)d_in[3];
    const float* davg    = (const float*)d_in[5];
    const float* dstd    = (const float*)d_in[6];
    const float* eW0     = (const float*)d_in[7];
    const float* eb0     = (const float*)d_in[8];
    const float* eW1     = (const float*)d_in[9];
    const float* eb1     = (const float*)d_in[10];
    const float* eW2     = (const float*)d_in[11];
    const float* eb2     = (const float*)d_in[12];
    const float* fW0     = (const float*)d_in[13];
    const float* fb0     = (const float*)d_in[14];
    const float* fW1     = (const float*)d_in[15];
    const float* fb1     = (const float*)d_in[16];
    const float* fW2     = (const float*)d_in[17];
    const float* fb2     = (const float*)d_in[18];
    const float* fW3     = (const float*)d_in[19];
    const float* fb3     = (const float*)d_in[20];
    const float* eshift  = (const float*)d_in[21];
    float* out = (float*)d_out;
    float* ws  = (float*)d_ws;

    if (ws_size >= WS_NEED) {
        unsigned short* u0 = (unsigned short*)((char*)ws + USH_BYTE);
        const int n_ids = N_W0 + N_W1 + N_W2 + N_B + N_W3 + N_EI;
        wtrans_kernel<<<(n_ids + 255) / 256, 256, 0, stream>>>(
            fW0, fW1, fW2, fb0, fb1, fb2, fW3, fb3, eshift, itype, ws, out);
        table_kernel<<<512, 256, 0, stream>>>(davg, dstd, eW0, eb0, eW1, eb1, eW2, eb2, ws);
        embed_kernel<<<NATOMS, 128, 0, stream>>>(itype, imagedr, davg, dstd, ws);
        gemm0_kernel<<<dim3(8, 128), 128, 0, stream>>>(
            u0 + D_U, u0 + W0T_U, ws + BIAS_F, u0 + H0_U);
        gemmr_kernel<<<dim3(8, 128), 64, 0, stream>>>(
            u0 + H0_U, u0 + W1T_U, ws + BIAS_F + 512, u0 + H0_U, u0 + H1_U,
            nullptr, nullptr, nullptr, 1);
        gemmr_kernel<<<dim3(8, 128), 64, 0, stream>>>(
            u0 + H1_U, u0 + W2T_U, ws + BIAS_F + 1024, u0 + H1_U, nullptr,
            ws + W3C_F, itype, out, 2);
        etot_kernel<<<BSZ, 256, 0, stream>>>(out);
    } else {
        dp_atom_kernel<<<NATOMS, 256, 0, stream>>>(itype, imagedr, davg, dstd,
            eW0, eb0, eW1, eb1, eW2, eb2,
            fW0, fb0, fW1, fb1, fW2, fb2, fW3, fb3, eshift, out);
        etot_kernel<<<BSZ, 256, 0, stream>>>(out);
    }
}

// Round 8
// 191.679 us; speedup vs baseline: 1.0584x; 1.0034x over previous
//
#include <hip/hip_runtime.h>
#include <math.h>

#define NT 2
#define BSZ 4
#define NAT 512
#define NATOMS 2048
#define NNEI 200
#define EMB 100
#define FITH 240
#define DDIM 1600
#define TBK 1024

// ---- ws layout ----
// float region: [0..8) table ranges; [16..1552) concat biases; [1552..2064) w3c;
// int   region: [2064..4112) perm, [4112..4114) counts
#define BIAS_F  16
#define W3C_F   (BIAS_F + 3 * 512)
#define PERM_I  2064
#define CNT_I   (PERM_I + 2048)
#define USH_BYTE 16512
#define TBL_U   0                          // 4*1024*100 = 409600
#define W0T_U   409600                     // [512][1600] = 819200
#define W1T_U   (W0T_U + 819200)           // [512][512]  = 262144
#define W2T_U   (W1T_U + 262144)           // 262144
#define D_U     (W2T_U + 262144)           // [2048][1600] = 3276800
#define H0_U    (D_U + 3276800)            // [2048][512] = 1048576
#define H1_U    (H0_U + 1048576)           // 1048576
#define USH_END (H1_U + 1048576)
#define WS_NEED ((size_t)USH_BYTE + (size_t)USH_END * 2)   // ~12.2 MB

#define N_W0 819200
#define N_W1 262144
#define N_W2 262144
#define N_B  1536
#define N_W3 512
#define N_EI 2048
#define N_WT (N_W0 + N_W1 + N_W2 + N_B + N_W3 + N_EI)      // 1347584
#define WT_BLK ((N_WT + 255) / 256)                        // 5264
#define TB_BLK 512

typedef short s8v __attribute__((ext_vector_type(8)));
typedef float f4v __attribute__((ext_vector_type(4)));

__device__ __forceinline__ float ftanh(float x) {
    float ax = fabsf(x);
    float e = __expf(2.0f * ax);
    float t = 1.0f - __fdividef(2.0f, e + 1.0f);
    return (x < 0.0f) ? -t : t;
}
__device__ __forceinline__ unsigned short f2bf(float f) {
    unsigned u = __float_as_uint(f);
    u += 0x7FFFu + ((u >> 16) & 1u);
    return (unsigned short)(u >> 16);
}
__device__ __forceinline__ float bf2f(unsigned short s) {
    return __uint_as_float(((unsigned)s) << 16);
}
__device__ __forceinline__ float calc_S(float R) {
    float Rsafe = (R > 1e-5f) ? R : 1.0f;
    float u = (R - 0.5f) * (1.0f / 5.5f);
    float uu = u * u;
    float mid = (u * uu * (-6.0f * uu + 15.0f * u - 10.0f) + 1.0f) / Rsafe;
    float S = 0.0f;
    if (R > 0.0f && R < 0.5f)      S = 1.0f / Rsafe;
    else if (R > 0.5f && R < 6.0f) S = mid;
    return S;
}

// ---------- K1: prep = wtrans + table build + type-perm (independent work, 1 launch) ----------
__global__ void __launch_bounds__(256) prep_kernel(
    const float* __restrict__ fW0, const float* __restrict__ fW1,
    const float* __restrict__ fW2,
    const float* __restrict__ fb0, const float* __restrict__ fb1,
    const float* __restrict__ fb2,
    const float* __restrict__ fW3, const float* __restrict__ fb3,
    const float* __restrict__ eshift,
    const float* __restrict__ davg, const float* __restrict__ dstd,
    const float* __restrict__ eW0, const float* __restrict__ eb0,
    const float* __restrict__ eW1, const float* __restrict__ eb1,
    const float* __restrict__ eW2, const float* __restrict__ eb2,
    const int* __restrict__ itype,
    float* __restrict__ ws, float* __restrict__ out)
{
    __shared__ float los[100], his[100];
    __shared__ float rng[2];
    __shared__ float h0s[8][25];
    __shared__ float h1s[8][50];
    __shared__ int pcnt, poff0, poff1;
    const int tid = threadIdx.x;
    int bxg = blockIdx.x;
    unsigned short* u0 = (unsigned short*)((char*)ws + USH_BYTE);

    if (bxg < WT_BLK) {
        // ---- weight transform ----
        int id = bxg * 256 + tid;
        if (id < N_W0) {
            int n = id / 1600, k = id - n * 1600;
            float v = 0.0f;
            if (n < 240)                  v = fW0[(size_t)k * 240 + n];
            else if (n >= 256 && n < 496) v = fW0[(size_t)(1600 + k) * 240 + (n - 256)];
            u0[W0T_U + id] = f2bf(v);
            return;
        }
        id -= N_W0;
        if (id < N_W1) {
            int n = id / 512, k = id - n * 512;
            float v = 0.0f;
            if (n < 240 && k < 240)       v = fW1[(size_t)k * 240 + n];
            else if (n >= 256 && n < 496 && k >= 256 && k < 496)
                                          v = fW1[(size_t)(240 + (k - 256)) * 240 + (n - 256)];
            u0[W1T_U + id] = f2bf(v);
            return;
        }
        id -= N_W1;
        if (id < N_W2) {
            int n = id / 512, k = id - n * 512;
            float v = 0.0f;
            if (n < 240 && k < 240)       v = fW2[(size_t)k * 240 + n];
            else if (n >= 256 && n < 496 && k >= 256 && k < 496)
                                          v = fW2[(size_t)(240 + (k - 256)) * 240 + (n - 256)];
            u0[W2T_U + id] = f2bf(v);
            return;
        }
        id -= N_W2;
        if (id < N_B) {
            int l = id / 512, n = id - l * 512;
            const float* fb = (l == 0) ? fb0 : (l == 1) ? fb1 : fb2;
            float v = 0.0f;
            if (n < 240)                  v = fb[n];
            else if (n >= 256 && n < 496) v = fb[240 + (n - 256)];
            ws[BIAS_F + l * 512 + n] = v;
            return;
        }
        id -= N_B;
        if (id < N_W3) {
            int n = id;
            float v = 0.0f;
            if (n < 240)                  v = fW3[n];
            else if (n >= 256 && n < 496) v = fW3[240 + (n - 256)];
            ws[W3C_F + n] = v;
            return;
        }
        id -= N_W3;
        if (id < N_EI) {
            int t = itype[id & (NAT - 1)];
            out[4 + id] = fb3[t] + eshift[t];
        }
        return;
    }
    bxg -= WT_BLK;
    if (bxg < TB_BLK) {
        // ---- embedding table build ----
        const int nid = bxg >> 7;
        const int kb  = (bxg & 127) * 8;
        const int t = nid >> 1, j = nid & 1;
        if (tid < 100) {
            int m = j * 100 + tid;
            float av = davg[(t * NNEI + m) * 4];
            float sd = dstd[(t * NNEI + m) * 4];
            float inv = __fdividef(1.0f, sd);
            float a = (0.0f - av) * inv;         // S in [0,2] for this data
            float b = (2.0f - av) * inv;
            los[tid] = fminf(a, b);
            his[tid] = fmaxf(a, b);
        }
        __syncthreads();
        if (tid == 0) {
            float lo = los[0], hi = his[0];
            for (int i = 1; i < 100; ++i) { lo = fminf(lo, los[i]); hi = fmaxf(hi, his[i]); }
            rng[0] = lo; rng[1] = hi - lo;
            if (kb == 0) {
                ws[nid * 2] = lo;
                ws[nid * 2 + 1] = (float)(TBK - 1) / (hi - lo);
            }
        }
        __syncthreads();
        const float smin = rng[0], span = rng[1];
        const float* W0 = eW0 + nid * 25;
        const float* B0 = eb0 + nid * 25;
        if (tid < 200) {
            int q = tid / 25, a = tid % 25;
            float s = smin + span * ((float)(kb + q) * (1.0f / (TBK - 1)));
            h0s[q][a] = ftanh(fmaf(s, W0[a], B0[a]));
        }
        __syncthreads();
        const float* W1 = eW1 + nid * 1250;
        const float* B1 = eb1 + nid * 50;
        for (int idx = tid; idx < 400; idx += 256) {
            int q = idx / 50, cc = idx % 50;
            float acc = B1[cc];
#pragma unroll
            for (int a = 0; a < 25; ++a) acc = fmaf(h0s[q][a], W1[a * 50 + cc], acc);
            h1s[q][cc] = ftanh(acc) + h0s[q][(cc < 25) ? cc : cc - 25];
        }
        __syncthreads();
        const float* W2 = eW2 + nid * 5000;
        const float* B2 = eb2 + nid * 100;
        unsigned short* tblu = u0 + TBL_U;
        for (int idx = tid; idx < 800; idx += 256) {
            int q = idx / 100, c = idx % 100;
            float acc = B2[c];
#pragma unroll
            for (int a = 0; a < 50; ++a) acc = fmaf(h1s[q][a], W2[a * 100 + c], acc);
            float g = ftanh(acc) + h1s[q][(c < 50) ? c : c - 50];
            tblu[(size_t)(nid * TBK + kb + q) * 100 + c] = f2bf(g);
        }
        return;
    }
    // ---- type partition perm ----
    if (tid == 0) { pcnt = 0; poff0 = 0; poff1 = 0; }
    __syncthreads();
    int* wsi = (int*)ws;
    int local0 = 0;
    for (int i = tid; i < NATOMS; i += 256) local0 += (itype[i & (NAT - 1)] == 0);
    atomicAdd(&pcnt, local0);
    __syncthreads();
    const int c0 = pcnt;
    for (int i = tid; i < NATOMS; i += 256) {
        int t = itype[i & (NAT - 1)];
        int pos = (t == 0) ? atomicAdd(&poff0, 1) : (c0 + atomicAdd(&poff1, 1));
        wsi[PERM_I + pos] = i;
    }
    if (tid == 0) { wsi[CNT_I] = c0; wsi[CNT_I + 1] = NATOMS - c0; }
}

// ---------- K2: embed (table interp) -> D bf16 [2048][1600] ----------
__global__ void __launch_bounds__(128) embed_kernel(
    const int* __restrict__ itype, const float* __restrict__ imagedr,
    const float* __restrict__ davg, const float* __restrict__ dstd,
    float* __restrict__ ws)
{
    __shared__ __align__(16) float4 srn[NNEI];
    __shared__ float sx[NNEI];
    __shared__ float part[2][400];
    const int atom = blockIdx.x;
    const int n = atom & (NAT - 1);
    const int tid = threadIdx.x;
    const int t = itype[n];
    unsigned short* u0 = (unsigned short*)((char*)ws + USH_BYTE);

    const float sm0 = ws[(t * 2 + 0) * 2], sc0 = ws[(t * 2 + 0) * 2 + 1];
    const float sm1 = ws[(t * 2 + 1) * 2], sc1 = ws[(t * 2 + 1) * 2 + 1];

    for (int m = tid; m < NNEI; m += 128) {
        float4 dr = ((const float4*)imagedr)[(size_t)atom * NNEI + m];
        float R = dr.x;
        float S = calc_S(R);
        float Rsafe = (R > 1e-5f) ? R : 1.0f;
        float sr = (fabsf(R) > 1e-5f) ? (S / Rsafe) : 0.0f;
        float4 av = ((const float4*)davg)[t * NNEI + m];
        float4 sd = ((const float4*)dstd)[t * NNEI + m];
        float4 rv;
        rv.x = (S         - av.x) / sd.x;
        rv.y = (sr * dr.y - av.y) / sd.y;
        rv.z = (sr * dr.z - av.z) / sd.z;
        rv.w = (sr * dr.w - av.w) / sd.w;
        srn[m] = rv;
        float smin = (m >= 100) ? sm1 : sm0;
        float scal = (m >= 100) ? sc1 : sc0;
        sx[m] = fminf(fmaxf((rv.x - smin) * scal, 0.0f), (float)(TBK - 2) + 0.9999f);
    }
    __syncthreads();

    const int w = tid >> 6, lane = tid & 63;
    const unsigned short* T = u0 + TBL_U + (size_t)(t * 2 + w) * TBK * EMB;
    const bool hi = (lane < 36);
    float xA0 = 0, xA1 = 0, xA2 = 0, xA3 = 0;
    float xB0 = 0, xB1 = 0, xB2 = 0, xB3 = 0;
#pragma unroll 4
    for (int mi = 0; mi < 100; ++mi) {
        int m = w * 100 + mi;
        float4 rv = srn[m];
        float x = sx[m];
        int i = (int)x;
        float f = x - (float)i;
        const unsigned short* Tr = T + (size_t)i * EMB;
        float g0 = bf2f(Tr[lane]);
        float g1 = bf2f(Tr[EMB + lane]);
        float g = fmaf(f, g1 - g0, g0);
        xA0 = fmaf(rv.x, g, xA0); xA1 = fmaf(rv.y, g, xA1);
        xA2 = fmaf(rv.z, g, xA2); xA3 = fmaf(rv.w, g, xA3);
        if (hi) {
            float h0v = bf2f(Tr[64 + lane]);
            float h1v = bf2f(Tr[EMB + 64 + lane]);
            float g2 = fmaf(f, h1v - h0v, h0v);
            xB0 = fmaf(rv.x, g2, xB0); xB1 = fmaf(rv.y, g2, xB1);
            xB2 = fmaf(rv.z, g2, xB2); xB3 = fmaf(rv.w, g2, xB3);
        }
    }
    part[w][0 * 100 + lane] = xA0; part[w][1 * 100 + lane] = xA1;
    part[w][2 * 100 + lane] = xA2; part[w][3 * 100 + lane] = xA3;
    if (hi) {
        part[w][0 * 100 + 64 + lane] = xB0; part[w][1 * 100 + 64 + lane] = xB1;
        part[w][2 * 100 + 64 + lane] = xB2; part[w][3 * 100 + 64 + lane] = xB3;
    }
    __syncthreads();
    const float inv = 1.0f / 200.0f;
    for (int idx = tid; idx < 400; idx += 128)
        part[0][idx] = (part[0][idx] + part[1][idx]) * inv;   // xyz[4][100]
    __syncthreads();
    unsigned short* Drow = u0 + D_U + (size_t)atom * DDIM;
    const float* xt = part[0];
    for (int idx = tid; idx < DDIM; idx += 128) {
        int c = idx >> 4, d = idx & 15;
        float s = xt[c] * xt[d] + xt[100 + c] * xt[100 + d]
                + xt[200 + c] * xt[200 + d] + xt[300 + c] * xt[300 + d];
        Drow[idx] = f2bf(s);
    }
}

// ---------- K3: layer-0 GEMM, type-partitioned rows, 2-wave k-split, 4 acc chains ----------
__global__ void __launch_bounds__(128) gemm0_kernel(
    const unsigned short* __restrict__ A,     // D [2048][1600]
    const unsigned short* __restrict__ BT,    // W0T [512][1600]
    const float* __restrict__ bias,
    const int* __restrict__ wsi,
    unsigned short* __restrict__ Out)         // H0 [2048][512]
{
    __shared__ float lred[64][17];
    const int z = blockIdx.z;
    const int cnt = wsi[CNT_I + z];
    const int my = blockIdx.y;
    if (my * 16 >= cnt) return;
    const int base = z ? wsi[CNT_I] : 0;
    const int tid = threadIdx.x;
    const int w = tid >> 6, lane = tid & 63;
    const int mr = lane & 15, q = lane >> 4;
    const int n0 = z * 256 + blockIdx.x * 64;
    const int m0 = my * 16;
    const int arow = wsi[PERM_I + base + min(m0 + mr, cnt - 1)];
    const unsigned short* Ap = A  + (size_t)arow * DDIM + w * 800 + q * 8;
    const unsigned short* Bp = BT + (size_t)(n0 + mr) * DDIM + w * 800 + q * 8;

    f4v a0 = {0,0,0,0}, a1 = {0,0,0,0}, a2 = {0,0,0,0}, a3 = {0,0,0,0};
#pragma unroll 5
    for (int kt = 0; kt < 25; ++kt) {
        s8v av = *(const s8v*)(Ap + kt * 32);
        s8v b0 = *(const s8v*)(Bp + kt * 32);
        s8v b1 = *(const s8v*)(Bp + 16 * DDIM + kt * 32);
        s8v b2 = *(const s8v*)(Bp + 32 * DDIM + kt * 32);
        s8v b3 = *(const s8v*)(Bp + 48 * DDIM + kt * 32);
        a0 = __builtin_amdgcn_mfma_f32_16x16x32_bf16(av, b0, a0, 0, 0, 0);
        a1 = __builtin_amdgcn_mfma_f32_16x16x32_bf16(av, b1, a1, 0, 0, 0);
        a2 = __builtin_amdgcn_mfma_f32_16x16x32_bf16(av, b2, a2, 0, 0, 0);
        a3 = __builtin_amdgcn_mfma_f32_16x16x32_bf16(av, b3, a3, 0, 0, 0);
    }
    if (w == 1) {
#pragma unroll
        for (int r = 0; r < 4; ++r) {
            lred[lane][r]      = a0[r];
            lred[lane][4 + r]  = a1[r];
            lred[lane][8 + r]  = a2[r];
            lred[lane][12 + r] = a3[r];
        }
    }
    __syncthreads();
    if (w == 0) {
#pragma unroll
        for (int j = 0; j < 4; ++j) {
            const int col = n0 + j * 16 + mr;
            const float bv = bias[col];
            f4v* ap = (j == 0) ? &a0 : (j == 1) ? &a1 : (j == 2) ? &a2 : &a3;
#pragma unroll
            for (int r = 0; r < 4; ++r) {
                int rl = m0 + q * 4 + r;
                if (rl < cnt) {
                    int orow = wsi[PERM_I + base + rl];
                    float s = (*ap)[r] + lred[lane][j * 4 + r] + bv;
                    Out[(size_t)orow * 512 + col] = f2bf(ftanh(s));
                }
            }
        }
    }
}

// ---------- K4: residual GEMM layers 1/2 — single wave, type-partitioned ----------
// mode 1: Out = Res + tanh(A x BT^T + bias)
// mode 2: Ei += ((Res + tanh(.)) . w3c) per row
__global__ void __launch_bounds__(64) gemmr_kernel(
    const unsigned short* __restrict__ A, const unsigned short* __restrict__ BT,
    const float* __restrict__ bias, const unsigned short* __restrict__ Res,
    unsigned short* __restrict__ Out,
    const float* __restrict__ w3c, const int* __restrict__ wsi,
    float* __restrict__ out, int mode)
{
    const int z = blockIdx.z;
    const int cnt = wsi[CNT_I + z];
    const int my = blockIdx.y;
    if (my * 16 >= cnt) return;
    const int base = z ? wsi[CNT_I] : 0;
    const int lane = threadIdx.x;
    const int mr = lane & 15, q = lane >> 4;
    const int n0 = z * 256 + blockIdx.x * 64;
    const int k0 = z * 256;
    const int m0 = my * 16;
    const int arow = wsi[PERM_I + base + min(m0 + mr, cnt - 1)];
    const unsigned short* Ap = A  + (size_t)arow * 512 + k0 + q * 8;
    const unsigned short* Bp = BT + (size_t)(n0 + mr) * 512 + k0 + q * 8;

    f4v a0 = {0,0,0,0}, a1 = {0,0,0,0}, a2 = {0,0,0,0}, a3 = {0,0,0,0};
#pragma unroll
    for (int kt = 0; kt < 8; ++kt) {
        s8v av = *(const s8v*)(Ap + kt * 32);
        s8v b0 = *(const s8v*)(Bp + kt * 32);
        s8v b1 = *(const s8v*)(Bp + 16 * 512 + kt * 32);
        s8v b2 = *(const s8v*)(Bp + 32 * 512 + kt * 32);
        s8v b3 = *(const s8v*)(Bp + 48 * 512 + kt * 32);
        a0 = __builtin_amdgcn_mfma_f32_16x16x32_bf16(av, b0, a0, 0, 0, 0);
        a1 = __builtin_amdgcn_mfma_f32_16x16x32_bf16(av, b1, a1, 0, 0, 0);
        a2 = __builtin_amdgcn_mfma_f32_16x16x32_bf16(av, b2, a2, 0, 0, 0);
        a3 = __builtin_amdgcn_mfma_f32_16x16x32_bf16(av, b3, a3, 0, 0, 0);
    }
    const float bv0 = bias[n0 + mr],      bv1 = bias[n0 + 16 + mr];
    const float bv2 = bias[n0 + 32 + mr], bv3 = bias[n0 + 48 + mr];
    if (mode == 1) {
#pragma unroll
        for (int r = 0; r < 4; ++r) {
            int rl = m0 + q * 4 + r;
            if (rl < cnt) {
                int orow = wsi[PERM_I + base + rl];
                size_t b_ = (size_t)orow * 512 + n0 + mr;
                Out[b_]      = f2bf(bf2f(Res[b_])      + ftanh(a0[r] + bv0));
                Out[b_ + 16] = f2bf(bf2f(Res[b_ + 16]) + ftanh(a1[r] + bv1));
                Out[b_ + 32] = f2bf(bf2f(Res[b_ + 32]) + ftanh(a2[r] + bv2));
                Out[b_ + 48] = f2bf(bf2f(Res[b_ + 48]) + ftanh(a3[r] + bv3));
            }
        }
    } else {
        const float w30 = w3c[n0 + mr],      w31 = w3c[n0 + 16 + mr];
        const float w32 = w3c[n0 + 32 + mr], w33 = w3c[n0 + 48 + mr];
#pragma unroll
        for (int r = 0; r < 4; ++r) {
            int rl = m0 + q * 4 + r;
            if (rl < cnt) {              // uniform across each 16-lane shfl group
                int orow = wsi[PERM_I + base + rl];
                size_t b_ = (size_t)orow * 512 + n0 + mr;
                float p = (bf2f(Res[b_])      + ftanh(a0[r] + bv0)) * w30
                        + (bf2f(Res[b_ + 16]) + ftanh(a1[r] + bv1)) * w31
                        + (bf2f(Res[b_ + 32]) + ftanh(a2[r] + bv2)) * w32
                        + (bf2f(Res[b_ + 48]) + ftanh(a3[r] + bv3)) * w33;
                p += __shfl_xor(p, 1, 16);
                p += __shfl_xor(p, 2, 16);
                p += __shfl_xor(p, 4, 16);
                p += __shfl_xor(p, 8, 16);
                if (mr == 0) atomicAdd(&out[4 + orow], p);
            }
        }
    }
}

// ---------- K5: Etot over Ei ----------
__global__ void etot_kernel(float* __restrict__ out) {
    const int b = blockIdx.x;
    float s = 0.0f;
    for (int n = threadIdx.x; n < NAT; n += 256) s += out[4 + b * NAT + n];
#pragma unroll
    for (int off = 32; off > 0; off >>= 1) s += __shfl_down(s, off, 64);
    __shared__ float rr[4];
    if ((threadIdx.x & 63) == 0) rr[threadIdx.x >> 6] = s;
    __syncthreads();
    if (threadIdx.x == 0) out[b] = rr[0] + rr[1] + rr[2] + rr[3];
}

// ================= fallback (small ws): monolithic per-atom =================
__global__ void dp_atom_kernel(
    const int* __restrict__ itype, const float* __restrict__ imagedr,
    const float* __restrict__ davg, const float* __restrict__ dstd,
    const float* __restrict__ eW0, const float* __restrict__ eb0,
    const float* __restrict__ eW1, const float* __restrict__ eb1,
    const float* __restrict__ eW2, const float* __restrict__ eb2,
    const float* __restrict__ fW0, const float* __restrict__ fb0,
    const float* __restrict__ fW1, const float* __restrict__ fb1,
    const float* __restrict__ fW2, const float* __restrict__ fb2,
    const float* __restrict__ fW3, const float* __restrict__ fb3,
    const float* __restrict__ eshift, float* __restrict__ out)
{
    __shared__ __align__(16) float4 rn4[NNEI];
    __shared__ __align__(16) float  xyz[4 * EMB];
    __shared__ __align__(16) float  h0s[100 * 25];
    __shared__ __align__(16) float  smem[100 * 52];
    const int atom = blockIdx.x;
    const int n = atom & (NAT - 1);
    const int tid = threadIdx.x;
    const int t = itype[n];
    for (int m = tid; m < NNEI; m += 256) {
        float4 dr = ((const float4*)imagedr)[(size_t)atom * NNEI + m];
        float R = dr.x;
        float S = calc_S(R);
        float Rsafe = (R > 1e-5f) ? R : 1.0f;
        float sr = (fabsf(R) > 1e-5f) ? (S / Rsafe) : 0.0f;
        float4 av = ((const float4*)davg)[t * NNEI + m];
        float4 sd = ((const float4*)dstd)[t * NNEI + m];
        float4 rv;
        rv.x = (S - av.x) / sd.x; rv.y = (sr * dr.y - av.y) / sd.y;
        rv.z = (sr * dr.z - av.z) / sd.z; rv.w = (sr * dr.w - av.w) / sd.w;
        rn4[m] = rv;
    }
    const int c = tid & 127; const int mh = tid >> 7;
    float xp0 = 0, xp1 = 0, xp2 = 0, xp3 = 0;
    for (int j = 0; j < NT; ++j) {
        const int wb = t * NT + j;
        const float* W0 = eW0 + wb * 25; const float* B0 = eb0 + wb * 25;
        const float* W1 = eW1 + wb * 1250; const float* B1 = eb1 + wb * 50;
        const float* W2 = eW2 + wb * 5000; const float* B2 = eb2 + wb * 100;
        __syncthreads();
        for (int idx = tid; idx < 2500; idx += 256) {
            int m = idx / 25, a = idx - m * 25;
            h0s[idx] = ftanh(fmaf(rn4[j * 100 + m].x, W0[a], B0[a]));
        }
        __syncthreads();
        for (int idx = tid; idx < 5000; idx += 256) {
            int m = idx / 50, cc = idx - m * 50;
            const float* h0m = h0s + m * 25;
            float acc = B1[cc];
#pragma unroll
            for (int a = 0; a < 25; ++a) acc = fmaf(h0m[a], W1[a * 50 + cc], acc);
            smem[m * 52 + cc] = ftanh(acc) + h0m[(cc < 25) ? cc : cc - 25];
        }
        for (int idx = tid; idx < 200; idx += 256)
            smem[(idx >> 1) * 52 + 50 + (idx & 1)] = 0.0f;
        __syncthreads();
        if (c < EMB) {
            float w2c[52];
#pragma unroll
            for (int a = 0; a < 50; ++a) w2c[a] = W2[a * EMB + c];
            w2c[50] = 0; w2c[51] = 0;
            const float bc = B2[c];
            const int sk = (c < 50) ? c : c - 50;
            for (int i = 0; i < 50; ++i) {
                int m = mh * 50 + i;
                const float* h1m = smem + m * 52;
                float acc = bc;
#pragma unroll
                for (int q = 0; q < 13; ++q) {
                    float4 hv = ((const float4*)h1m)[q];
                    acc = fmaf(hv.x, w2c[4 * q], acc); acc = fmaf(hv.y, w2c[4 * q + 1], acc);
                    acc = fmaf(hv.z, w2c[4 * q + 2], acc); acc = fmaf(hv.w, w2c[4 * q + 3], acc);
                }
                float g = ftanh(acc) + h1m[sk];
                float4 rm = rn4[j * 100 + m];
                xp0 = fmaf(rm.x, g, xp0); xp1 = fmaf(rm.y, g, xp1);
                xp2 = fmaf(rm.z, g, xp2); xp3 = fmaf(rm.w, g, xp3);
            }
        }
    }
    __syncthreads();
    const float inv = 1.0f / 200.0f;
    if (mh == 0 && c < EMB) {
        xyz[c] = xp0 * inv; xyz[EMB + c] = xp1 * inv;
        xyz[2 * EMB + c] = xp2 * inv; xyz[3 * EMB + c] = xp3 * inv;
    }
    __syncthreads();
    if (mh == 1 && c < EMB) {
        xyz[c] += xp0 * inv; xyz[EMB + c] += xp1 * inv;
        xyz[2 * EMB + c] += xp2 * inv; xyz[3 * EMB + c] += xp3 * inv;
    }
    __syncthreads();
    float* Dld = smem;
    for (int idx = tid; idx < DDIM; idx += 256) {
        int cc = idx >> 4, d = idx & 15;
        Dld[idx] = xyz[cc] * xyz[d] + xyz[EMB + cc] * xyz[EMB + d]
                 + xyz[2 * EMB + cc] * xyz[2 * EMB + d] + xyz[3 * EMB + cc] * xyz[3 * EMB + d];
    }
    __syncthreads();
    float* hA = smem + DDIM; float* hB = hA + FITH; float* h2 = hB + FITH; float* red = h2 + FITH;
    if (tid < FITH) {
        const float* W = fW0 + (size_t)t * DDIM * FITH;
        float acc = fb0[t * FITH + tid];
        for (int f = 0; f < DDIM; f += 4) {
            float4 dv = *(const float4*)(Dld + f);
            acc = fmaf(dv.x, W[f * FITH + tid], acc); acc = fmaf(dv.y, W[(f + 1) * FITH + tid], acc);
            acc = fmaf(dv.z, W[(f + 2) * FITH + tid], acc); acc = fmaf(dv.w, W[(f + 3) * FITH + tid], acc);
        }
        hA[tid] = ftanh(acc);
    }
    __syncthreads();
    if (tid < FITH) {
        const float* W = fW1 + t * FITH * FITH;
        float acc = fb1[t * FITH + tid];
        for (int f = 0; f < FITH; f += 4) {
            float4 hv = *(const float4*)(hA + f);
            acc = fmaf(hv.x, W[f * FITH + tid], acc); acc = fmaf(hv.y, W[(f + 1) * FITH + tid], acc);
            acc = fmaf(hv.z, W[(f + 2) * FITH + tid], acc); acc = fmaf(hv.w, W[(f + 3) * FITH + tid], acc);
        }
        hB[tid] = hA[tid] + ftanh(acc);
    }
    __syncthreads();
    if (tid < FITH) {
        const float* W = fW2 + t * FITH * FITH;
        float acc = fb2[t * FITH + tid];
        for (int f = 0; f < FITH; f += 4) {
            float4 hv = *(const float4*)(hB + f);
            acc = fmaf(hv.x, W[f * FITH + tid], acc); acc = fmaf(hv.y, W[(f + 1) * FITH + tid], acc);
            acc = fmaf(hv.z, W[(f + 2) * FITH + tid], acc); acc = fmaf(hv.w, W[(f + 3) * FITH + tid], acc);
        }
        h2[tid] = hB[tid] + ftanh(acc);
    }
    __syncthreads();
    float p = (tid < FITH) ? h2[tid] * fW3[t * FITH + tid] : 0.0f;
#pragma unroll
    for (int off = 32; off > 0; off >>= 1) p += __shfl_down(p, off, 64);
    if ((tid & 63) == 0) red[tid >> 6] = p;
    __syncthreads();
    if (tid == 0) out[4 + atom] = red[0] + red[1] + red[2] + red[3] + fb3[t] + eshift[t];
}

extern "C" void kernel_launch(void* const* d_in, const int* in_sizes, int n_in,
                              void* d_out, int out_size, void* d_ws, size_t ws_size,
                              hipStream_t stream) {
    const int*   itype   = (const int*)  d_in[1];
    const float* imagedr = (const float*)d_in[3];
    const float* davg    = (const float*)d_in[5];
    const float* dstd    = (const float*)d_in[6];
    const float* eW0     = (const float*)d_in[7];
    const float* eb0     = (const float*)d_in[8];
    const float* eW1     = (const float*)d_in[9];
    const float* eb1     = (const float*)d_in[10];
    const float* eW2     = (const float*)d_in[11];
    const float* eb2     = (const float*)d_in[12];
    const float* fW0     = (const float*)d_in[13];
    const float* fb0     = (const float*)d_in[14];
    const float* fW1     = (const float*)d_in[15];
    const float* fb1     = (const float*)d_in[16];
    const float* fW2     = (const float*)d_in[17];
    const float* fb2     = (const float*)d_in[18];
    const float* fW3     = (const float*)d_in[19];
    const float* fb3     = (const float*)d_in[20];
    const float* eshift  = (const float*)d_in[21];
    float* out = (float*)d_out;
    float* ws  = (float*)d_ws;

    if (ws_size >= WS_NEED) {
        unsigned short* u0 = (unsigned short*)((char*)ws + USH_BYTE);
        const int* wsi = (const int*)ws;
        prep_kernel<<<WT_BLK + TB_BLK + 1, 256, 0, stream>>>(
            fW0, fW1, fW2, fb0, fb1, fb2, fW3, fb3, eshift,
            davg, dstd, eW0, eb0, eW1, eb1, eW2, eb2, itype, ws, out);
        embed_kernel<<<NATOMS, 128, 0, stream>>>(itype, imagedr, davg, dstd, ws);
        gemm0_kernel<<<dim3(4, 128, 2), 128, 0, stream>>>(
            u0 + D_U, u0 + W0T_U, ws + BIAS_F, wsi, u0 + H0_U);
        gemmr_kernel<<<dim3(4, 128, 2), 64, 0, stream>>>(
            u0 + H0_U, u0 + W1T_U, ws + BIAS_F + 512, u0 + H0_U, u0 + H1_U,
            nullptr, wsi, nullptr, 1);
        gemmr_kernel<<<dim3(4, 128, 2), 64, 0, stream>>>(
            u0 + H1_U, u0 + W2T_U, ws + BIAS_F + 1024, u0 + H1_U, nullptr,
            ws + W3C_F, wsi, out, 2);
        etot_kernel<<<BSZ, 256, 0, stream>>>(out);
    } else {
        dp_atom_kernel<<<NATOMS, 256, 0, stream>>>(itype, imagedr, davg, dstd,
            eW0, eb0, eW1, eb1, eW2, eb2,
            fW0, fb0, fW1, fb1, fW2, fb2, fW3, fb3, eshift, out);
        etot_kernel<<<BSZ, 256, 0, stream>>>(out);
    }
}